// Round 5
// baseline (252.816 us; speedup 1.0000x reference)
//
#include <hip/hip_runtime.h>
#include <stdint.h>

typedef int   i32x8  __attribute__((ext_vector_type(8)));
typedef float f32x16 __attribute__((ext_vector_type(16)));

#define B_ROWS 8192
#define D_DIM  512
#define GRID_SIMMIN 2048

// monotone float<->uint encoding: enc order == float order (uint atomicMin
// == float min). f>=0: set sign bit; f<0: bitwise NOT.
__device__ __forceinline__ uint32_t enc_f32(float f) {
  uint32_t s = __float_as_uint(f);
  return (s & 0x80000000u) ? ~s : (s | 0x80000000u);
}
__device__ __forceinline__ float dec_f32(uint32_t e) {
  uint32_t s = (e & 0x80000000u) ? (e ^ 0x80000000u) : ~e;
  return __uint_as_float(s);
}

// ---------------------------------------------------------------------------
// Kernel 1: per-row normalize (fp32 -> fp8 e4m3) + cos(anchor, positive).
// Wave per row. Inits minenc[r]=+inf-enc and zeroes the done-counter.
// ---------------------------------------------------------------------------
__global__ __launch_bounds__(256) void norm_kernel(
    const float* __restrict__ anchor, const float* __restrict__ positive,
    uint32_t* __restrict__ a8, uint32_t* __restrict__ p8,
    float* __restrict__ cos_ap, uint32_t* __restrict__ minenc,
    uint32_t* __restrict__ donecnt)
{
  const int wave = threadIdx.x >> 6, lane = threadIdx.x & 63;
  const int r = blockIdx.x * 4 + wave;

  const float4* av = (const float4*)(anchor   + (size_t)r * D_DIM) + lane * 2;
  const float4* pv = (const float4*)(positive + (size_t)r * D_DIM) + lane * 2;
  float4 a0 = av[0], a1 = av[1];
  float4 p0 = pv[0], p1 = pv[1];

  float sa = a0.x*a0.x + a0.y*a0.y + a0.z*a0.z + a0.w*a0.w
           + a1.x*a1.x + a1.y*a1.y + a1.z*a1.z + a1.w*a1.w;
  float sp = p0.x*p0.x + p0.y*p0.y + p0.z*p0.z + p0.w*p0.w
           + p1.x*p1.x + p1.y*p1.y + p1.z*p1.z + p1.w*p1.w;
  float dp = a0.x*p0.x + a0.y*p0.y + a0.z*p0.z + a0.w*p0.w
           + a1.x*p1.x + a1.y*p1.y + a1.z*p1.z + a1.w*p1.w;

#pragma unroll
  for (int d = 1; d < 64; d <<= 1) {
    sa += __shfl_xor(sa, d);
    sp += __shfl_xor(sp, d);
    dp += __shfl_xor(dp, d);
  }

  const float na = sqrtf(sa), np = sqrtf(sp);
  const float ia = 1.0f / na, ip = 1.0f / np;

  float na0 = a0.x*ia, na1 = a0.y*ia, na2 = a0.z*ia, na3 = a0.w*ia;
  float na4 = a1.x*ia, na5 = a1.y*ia, na6 = a1.z*ia, na7 = a1.w*ia;
  float np0 = p0.x*ip, np1 = p0.y*ip, np2 = p0.z*ip, np3 = p0.w*ip;
  float np4 = p1.x*ip, np5 = p1.y*ip, np6 = p1.z*ip, np7 = p1.w*ip;

  uint32_t aw0 = __builtin_amdgcn_cvt_pk_fp8_f32(na0, na1, 0,  false);
  aw0          = __builtin_amdgcn_cvt_pk_fp8_f32(na2, na3, aw0, true);
  uint32_t aw1 = __builtin_amdgcn_cvt_pk_fp8_f32(na4, na5, 0,  false);
  aw1          = __builtin_amdgcn_cvt_pk_fp8_f32(na6, na7, aw1, true);
  uint32_t pw0 = __builtin_amdgcn_cvt_pk_fp8_f32(np0, np1, 0,  false);
  pw0          = __builtin_amdgcn_cvt_pk_fp8_f32(np2, np3, pw0, true);
  uint32_t pw1 = __builtin_amdgcn_cvt_pk_fp8_f32(np4, np5, 0,  false);
  pw1          = __builtin_amdgcn_cvt_pk_fp8_f32(np6, np7, pw1, true);

  ((uint2*)a8)[(size_t)r * 64 + lane] = make_uint2(aw0, aw1);
  ((uint2*)p8)[(size_t)r * 64 + lane] = make_uint2(pw0, pw1);

  if (lane == 0) {
    cos_ap[r] = dp / fmaxf(na * np, 1e-8f);
    minenc[r] = 0xFFFFFFFFu;   // +inf in monotone encoding
  }
  if (blockIdx.x == 0 && threadIdx.x == 0) *donecnt = 0u;
}

// ---------------------------------------------------------------------------
// global -> LDS direct load, 16B per lane (dest = wave-uniform base + lane*16).
// ---------------------------------------------------------------------------
__device__ __forceinline__ void load16_to_lds(const void* g, void* l) {
  __builtin_amdgcn_global_load_lds(
      (__attribute__((address_space(1))) uint32_t*)(uintptr_t)(g),
      (__attribute__((address_space(3))) uint32_t*)(uintptr_t)(l),
      16, 0, 0);
}

// ---------------------------------------------------------------------------
// Kernel 2: sim = A_n * P_n^T via 32x32x64 MX-fp8 MFMA (scale=1.0), fused
// diag-masked row-min -> device atomicMin, fused last-block finalize.
//
// R4 post-mortem: invariant limiter was the LDS pipe (16 b128 reads per 16
// mfma/wave; LDS demand ~2.3x matrix demand). This round: 32x32x64 mfma
// (2x FLOP per operand byte) + asymmetric 128m x 64n wave tile ->
// 12 b128 reads per 8 mfma/wave: LDS ~= matrix ~= 1.1 K cyc/CU/iter.
// Block tile 128 x 256 (4 waves in n), BK=64, double-buffered (48 KB LDS).
// LDS slot swizzle s ^= (row>>1)&3 -> bank-uniform frag reads.
// ---------------------------------------------------------------------------
__global__ __launch_bounds__(256, 2) void simmin_kernel(
    const uint8_t* __restrict__ a8, const uint8_t* __restrict__ p8,
    uint32_t* __restrict__ minenc, const float* __restrict__ cos_ap,
    uint32_t* __restrict__ donecnt, float* __restrict__ out)
{
  __shared__ __attribute__((aligned(16))) uint8_t Alds[2][128 * 64];
  __shared__ __attribute__((aligned(16))) uint8_t Plds[2][256 * 64];
  __shared__ float redmin[4][128];
  __shared__ int   isLast;

  const int tid  = threadIdx.x;
  const int lane = tid & 63;
  const int wave = tid >> 6;        // wave owns cols [wave*64, wave*64+64)
  const int half = lane >> 5;       // k-half selector in frag layout
  const int r31  = lane & 31;

  // XCD super-tile swizzle: xcd=bid&7 keeps 8 A-rowTiles L2-resident
  const int bid = blockIdx.x;
  const int blockRow = (bid & 7) * 8 + ((bid >> 3) & 7);  // 0..63
  const int blockCol = bid >> 6;                          // 0..31

  f32x16 acc[4][2];
#pragma unroll
  for (int i = 0; i < 4; i++)
#pragma unroll
    for (int j = 0; j < 2; j++)
#pragma unroll
      for (int e = 0; e < 16; e++) acc[i][j][e] = 0.f;

  const uint8_t* aBase = a8 + (size_t)(blockRow * 128) * D_DIM;
  const uint8_t* pBase = p8 + (size_t)(blockCol * 256) * D_DIM;

  // staging: one glds = 16 rows x 4 slots; lane: row=g*16+(lane>>2),
  // slot' = lane&3 (LDS side contiguous), global slot = slot'^((row>>1)&3)
  const int sRowOff = lane >> 2;
  const int sSlot   = lane & 3;

  auto stage = [&](int k0, int buf) {
#pragma unroll
    for (int c = 0; c < 2; c++) {
      const int g = wave * 2 + c;                 // 0..7 (A: 128 rows)
      const int rowL = g * 16 + sRowOff;
      const int sp = sSlot ^ ((rowL >> 1) & 3);
      load16_to_lds(aBase + (size_t)rowL * D_DIM + k0 + sp * 16,
                    &Alds[buf][g * 1024]);
    }
#pragma unroll
    for (int c = 0; c < 4; c++) {
      const int g = wave * 4 + c;                 // 0..15 (P: 256 rows)
      const int rowL = g * 16 + sRowOff;
      const int sp = sSlot ^ ((rowL >> 1) & 3);
      load16_to_lds(pBase + (size_t)rowL * D_DIM + k0 + sp * 16,
                    &Plds[buf][g * 1024]);
    }
  };

  stage(0, 0);

#pragma unroll
  for (int k = 0; k < 8; k++) {
    __syncthreads();
    const int buf = k & 1;

    // frag: lane reads 32B at (row=rowL, k=half*32..+32), swizzled slots
    i32x8 af[4], bf2[2];
#pragma unroll
    for (int mf = 0; mf < 4; mf++) {
      const int rowL = mf * 32 + r31;
      const int f = (rowL >> 1) & 3;
      const int4 lo = *(const int4*)&Alds[buf][rowL * 64 + (((half*2  ) ^ f) * 16)];
      const int4 hi = *(const int4*)&Alds[buf][rowL * 64 + (((half*2+1) ^ f) * 16)];
      af[mf] = (i32x8){lo.x, lo.y, lo.z, lo.w, hi.x, hi.y, hi.z, hi.w};
    }
#pragma unroll
    for (int nf = 0; nf < 2; nf++) {
      const int rowL = wave * 64 + nf * 32 + r31;
      const int f = (rowL >> 1) & 3;
      const int4 lo = *(const int4*)&Plds[buf][rowL * 64 + (((half*2  ) ^ f) * 16)];
      const int4 hi = *(const int4*)&Plds[buf][rowL * 64 + (((half*2+1) ^ f) * 16)];
      bf2[nf] = (i32x8){lo.x, lo.y, lo.z, lo.w, hi.x, hi.y, hi.z, hi.w};
    }

    if (k < 7) stage((k + 1) * 64, (k + 1) & 1);  // prefetch next tile

#pragma unroll
    for (int mf = 0; mf < 4; mf++)
#pragma unroll
      for (int nf = 0; nf < 2; nf++)
        acc[mf][nf] = __builtin_amdgcn_mfma_scale_f32_32x32x64_f8f6f4(
            af[mf], bf2[nf], acc[mf][nf],
            0, 0,                 // cbsz=fp8(e4m3) A, blgp=fp8(e4m3) B
            0, 0x7F7F7F7F,        // scale A (2^0)
            0, 0x7F7F7F7F);       // scale B (2^0)
  }

  // ---- epilogue: diag-masked row-min over this block's 256 cols
  // C/D 32x32 layout: row = (reg&3) + 8*(reg>>2) + 4*half, col = lane&31
  float rm[4][16];
#pragma unroll
  for (int mf = 0; mf < 4; mf++)
#pragma unroll
    for (int g = 0; g < 16; g++) rm[mf][g] = 3.0e38f;

#pragma unroll
  for (int mf = 0; mf < 4; mf++) {
#pragma unroll
    for (int nf = 0; nf < 2; nf++) {
      const int col = blockCol * 256 + wave * 64 + nf * 32 + r31;
#pragma unroll
      for (int g = 0; g < 16; g++) {
        const int row = blockRow * 128 + mf * 32 + (g & 3) + 8 * (g >> 2) + 4 * half;
        const float v = acc[mf][nf][g];
        rm[mf][g] = (row == col) ? rm[mf][g] : fminf(rm[mf][g], v);
      }
    }
  }
  // butterfly min over the 32 col-lanes (bit5 = half stays fixed)
#pragma unroll
  for (int d = 1; d < 32; d <<= 1)
#pragma unroll
    for (int mf = 0; mf < 4; mf++)
#pragma unroll
      for (int g = 0; g < 16; g++)
        rm[mf][g] = fminf(rm[mf][g], __shfl_xor(rm[mf][g], d));

  if (r31 == 0) {
#pragma unroll
    for (int mf = 0; mf < 4; mf++)
#pragma unroll
      for (int g = 0; g < 16; g++)
        redmin[wave][mf * 32 + (g & 3) + 8 * (g >> 2) + 4 * half] = rm[mf][g];
  }
  __syncthreads();

  if (tid < 128) {
    const float m = fminf(fminf(redmin[0][tid], redmin[1][tid]),
                          fminf(redmin[2][tid], redmin[3][tid]));
    atomicMin(&minenc[blockRow * 128 + tid], enc_f32(m));  // device-scope
  }

  // ---- fused finalize: last block to finish reduces the loss
  __threadfence();
  __syncthreads();   // all atomicMins of this block drained (vmcnt before barrier)
  if (tid == 0) {
    const uint32_t old = atomicAdd(donecnt, 1u);
    isLast = (old == (uint32_t)(GRID_SIMMIN - 1));
  }
  __syncthreads();
  if (isLast) {
    float sum = 0.0f;
    for (int r = tid; r < B_ROWS; r += 256) {
      const uint32_t e = atomicOr(&minenc[r], 0u);  // device-scope atomic read
      sum += fmaxf(0.0f, 1.0f + cos_ap[r] - dec_f32(e));
    }
#pragma unroll
    for (int d = 1; d < 64; d <<= 1) sum += __shfl_xor(sum, d);
    if ((tid & 63) == 0) redmin[0][tid >> 6] = sum;
    __syncthreads();
    if (tid == 0)
      out[0] = (redmin[0][0] + redmin[0][1] + redmin[0][2] + redmin[0][3])
               * (1.0f / (float)B_ROWS);
  }
}

// ---------------------------------------------------------------------------
extern "C" void kernel_launch(void* const* d_in, const int* in_sizes, int n_in,
                              void* d_out, int out_size, void* d_ws, size_t ws_size,
                              hipStream_t stream) {
  const float* anchor   = (const float*)d_in[0];
  const float* positive = (const float*)d_in[1];

  char* ws = (char*)d_ws;
  uint32_t* a8      = (uint32_t*)(ws);                                // 4 MB
  uint32_t* p8      = (uint32_t*)(ws + (4ull << 20));                 // 4 MB
  float*    cos_ap  = (float*)(ws + (8ull << 20));                    // 32 KB
  uint32_t* minenc  = (uint32_t*)(ws + (8ull << 20) + (32ull << 10)); // 32 KB
  uint32_t* donecnt = (uint32_t*)(ws + (8ull << 20) + (64ull << 10));
  float*    out = (float*)d_out;

  norm_kernel<<<B_ROWS / 4, 256, 0, stream>>>(anchor, positive, a8, p8,
                                              cos_ap, minenc, donecnt);
  simmin_kernel<<<GRID_SIMMIN, 256, 0, stream>>>((const uint8_t*)a8,
                                                 (const uint8_t*)p8, minenc,
                                                 cos_ap, donecnt, out);
}